// Round 5
// baseline (176.780 us; speedup 1.0000x reference)
//
#include <hip/hip_runtime.h>
#include <hip/hip_bf16.h>
#include <hip/hip_fp16.h>

// Problem constants
#define BB   4
#define CC   64
#define SS   8
#define NN   (32*64*64)   // 131072
#define NH_  4
#define HD_  16
#define TN   512          // n-tile for stage-1 kernel (fp16 LDS)
#define BPB  128          // blocks per batch in stage-1 kernel

// ---------------------------------------------------------------------------
// Kernel A: stage-1 pass over x.  512 threads/block, fp16 LDS tile.
// Per (b,n): e_s = exp(<sn_s, x/||x||>)  (sim in [-1,1] -> drop max-subtract)
// Per-block partials: U[s][c] = sum_n x[c,n]*e_s[n], L[s] = sum_n e_s[n]
// xt layout: row c = 512 halfs = 64 16B-slots; slot = j ^ (c&7) (XOR in low 3)
//  -> dot-phase column reads conflict-free; accumulate x-reads at bank floor;
//     e-reads wave-uniform (s constant per wave) -> pure broadcast.
// ---------------------------------------------------------------------------
__global__ __launch_bounds__(512, 4) void k_slots_attn(
    const float* __restrict__ x, const float* __restrict__ slot_init,
    float* __restrict__ U_part, float* __restrict__ sume_part)
{
    __shared__ __half xt[CC * TN];     // 64 KB
    __shared__ __half et[SS * TN];     // 8 KB
    __shared__ float  snT[SS * CC];    // 2 KB, [s][c]
    __shared__ float  snorm[SS];

    const int tid = threadIdx.x;
    const int b   = blockIdx.x / BPB;
    const int blk = blockIdx.x % BPB;

    // normalized slot vectors (slot_init is (1,C,S) -> same for all b)
    if (tid < SS) {
        float ss = 0.f;
        for (int c = 0; c < CC; ++c) { float v = slot_init[c*SS + tid]; ss += v*v; }
        snorm[tid] = fmaxf(sqrtf(ss), 1e-12f);
    }
    __syncthreads();
    if (tid < CC) {
        for (int s = 0; s < SS; ++s) snT[s*CC + tid] = slot_init[tid*SS + s] / snorm[s];
    }
    __syncthreads();

    const int s_own = tid >> 6;        // 0..7  (uniform per wave)
    const int c_own = tid & 63;        // 0..63
    float acc0 = 0.f, accS = 0.f;

    const float* xb = x + (size_t)b * CC * NN;
    const int crow = tid >> 3;         // stage row 0..63
    const int jg   = tid & 7;          // 64-float chunk within row
    const int ntiles = NN / TN;        // 256

    for (int t = blk; t < ntiles; t += BPB) {   // 2 iterations
        const int n0 = t * TN;

        // ---- stage: global float4 -> fp16 swizzled LDS ----
        {
            const float* src = xb + (size_t)crow * NN + n0 + jg*64;
            #pragma unroll
            for (int w = 0; w < 8; ++w) {
                float4 va = *(const float4*)(src + w*8);
                float4 vb = *(const float4*)(src + w*8 + 4);
                union { __half2 h2[4]; float4 f4; } u;
                u.h2[0] = __floats2half2_rn(va.x, va.y);
                u.h2[1] = __floats2half2_rn(va.z, va.w);
                u.h2[2] = __floats2half2_rn(vb.x, vb.y);
                u.h2[3] = __floats2half2_rn(vb.z, vb.w);
                const int slot = jg*8 + (w ^ (crow & 7));
                *(float4*)&xt[crow*TN + slot*8] = u.f4;
            }
        }
        __syncthreads();

        // ---- dots: thread owns column np = tid ----
        {
            const int qb = tid >> 3, lo = tid & 7;
            float ss = 0.f;
            float a[SS];
            #pragma unroll
            for (int s = 0; s < SS; ++s) a[s] = 0.f;
            #pragma unroll
            for (int c4 = 0; c4 < 16; ++c4) {
                float xv[4];
                #pragma unroll
                for (int jj = 0; jj < 4; ++jj) {
                    const int c = c4*4 + jj;
                    xv[jj] = __half2float(xt[c*TN + ((qb ^ (c & 7)) << 3) + lo]);
                    ss += xv[jj] * xv[jj];
                }
                #pragma unroll
                for (int s = 0; s < SS; ++s) {
                    float4 g4 = *(const float4*)(&snT[s*CC + c4*4]);
                    a[s] += g4.x*xv[0] + g4.y*xv[1] + g4.z*xv[2] + g4.w*xv[3];
                }
            }
            const float invn = 1.f / fmaxf(sqrtf(ss), 1e-12f);
            #pragma unroll
            for (int s = 0; s < SS; ++s)
                et[s*TN + tid] = __float2half(__expf(a[s] * invn));
        }
        __syncthreads();

        // ---- accumulate: thread owns (s_own, c_own); e-reads broadcast ----
        {
            const __half* xrow = &xt[c_own*TN];
            const __half* erow = &et[s_own*TN];
            const int cs = c_own & 7;
            #pragma unroll 4
            for (int j = 0; j < TN/8; ++j) {
                float4 eraw = *(const float4*)&erow[j*8];
                float4 xraw = *(const float4*)&xrow[(j ^ cs)*8];
                const __half2* eh = (const __half2*)&eraw;
                const __half2* xh = (const __half2*)&xraw;
                #pragma unroll
                for (int k = 0; k < 4; ++k) {
                    float2 ef = __half22float2(eh[k]);
                    float2 xf = __half22float2(xh[k]);
                    acc0 += ef.x*xf.x + ef.y*xf.y;
                    accS += ef.x + ef.y;
                }
            }
        }
        __syncthreads();
    }

    size_t base = (((size_t)b * BPB + blk) * SS + s_own) * CC;
    U_part[base + c_own] = acc0;
    if (c_own == 0)
        sume_part[((size_t)b * BPB + blk) * SS + s_own] = accS;
}

// ---------------------------------------------------------------------------
// Kernel P: precompute slot-independent folds of the feature path.
//   M[cp][c] = sum_o s2fw[o][cp] * fw[o][c];  g0[c] = sum_o s2fb[o]*fw[o][c]
//   hv[cp]   = sum_o s2fw[o][cp] * fb[o];     h0    = sum_o s2fb[o]*fb[o]
// ---------------------------------------------------------------------------
__global__ __launch_bounds__(256) void k_precomp(
    const float* __restrict__ s2fw, const float* __restrict__ s2fb,
    const float* __restrict__ fw, const float* __restrict__ fb,
    float* __restrict__ M, float* __restrict__ g0v,
    float* __restrict__ hv, float* __restrict__ h0)
{
    const int tid = threadIdx.x;
    if (blockIdx.x < 16) {
        const int cp = blockIdx.x*4 + (tid >> 6);
        const int c  = tid & 63;
        float acc = 0.f;
        #pragma unroll 8
        for (int o = 0; o < CC; ++o)
            acc += s2fw[o*CC + cp] * fw[o*CC + c];
        M[cp*CC + c] = acc;
    } else {
        if (tid < 64) {
            float acc = 0.f;
            #pragma unroll 8
            for (int o = 0; o < CC; ++o) acc += s2fb[o] * fw[o*CC + tid];
            g0v[tid] = acc;
        } else if (tid < 128) {
            const int cp = tid - 64;
            float acc = 0.f;
            #pragma unroll 8
            for (int o = 0; o < CC; ++o) acc += s2fw[o*CC + cp] * fb[o];
            hv[cp] = acc;
        } else if (tid == 128) {
            float acc = 0.f;
            for (int o = 0; o < CC; ++o) acc += s2fb[o] * fb[o];
            *h0 = acc;
        }
    }
}

// ---------------------------------------------------------------------------
// Kernel R: parallel reduce of partials -> upd[b,s,c] = U/L directly.
// ---------------------------------------------------------------------------
__global__ __launch_bounds__(256) void k_reduce2(
    const float* __restrict__ U_part, const float* __restrict__ sume_part,
    float* __restrict__ upd_g)
{
    __shared__ float part[4][64];
    __shared__ float lbuf[128];
    __shared__ float Lsh;
    const int tid = threadIdx.x;
    const int b = blockIdx.x >> 3, s = blockIdx.x & 7;
    const int c = tid & 63, kc = tid >> 6;

    float lv = 0.f;
    if (tid < 128) lv = sume_part[(size_t)(b*BPB + tid)*SS + s];

    float acc = 0.f;
    const float* base = U_part + ((size_t)(b*BPB + kc*32)*SS + s)*CC + c;
    #pragma unroll 8
    for (int k = 0; k < 32; ++k)
        acc += base[(size_t)k * SS * CC];
    part[kc][c] = acc;
    if (tid < 128) lbuf[tid] = lv;
    __syncthreads();

    if (tid < 64) {
        float v = lbuf[tid] + lbuf[tid + 64];
        v += __shfl_xor(v, 1); v += __shfl_xor(v, 2); v += __shfl_xor(v, 4);
        v += __shfl_xor(v, 8); v += __shfl_xor(v, 16); v += __shfl_xor(v, 32);
        if (tid == 0) Lsh = v;
    }
    __syncthreads();

    if (tid < 64) {
        float u = part[0][c] + part[1][c] + part[2][c] + part[3][c];
        upd_g[((size_t)b*SS + s)*CC + c] = u / Lsh;
    }
}

// ---------------------------------------------------------------------------
// Kernel B: slot pipeline. 4 blocks (one per batch), 256 threads.
// ---------------------------------------------------------------------------
__global__ __launch_bounds__(256) void k_slots_small(
    const float* __restrict__ upd_g,
    const float* __restrict__ spw, const float* __restrict__ spb,
    const float* __restrict__ lng, const float* __restrict__ lnb,
    const float* __restrict__ ipw, const float* __restrict__ ipb,
    const float* __restrict__ opw, const float* __restrict__ opb,
    const float* __restrict__ M, const float* __restrict__ g0v,
    const float* __restrict__ hv, const float* __restrict__ h0,
    float* __restrict__ st_out, float* __restrict__ g_out, float* __restrict__ h_out)
{
    __shared__ float upd[SS*CC];
    __shared__ float st [SS*CC];
    __shared__ float snb[SS*CC];
    __shared__ float qkv[SS*3*CC];
    __shared__ float ot [SS*CC];

    const int tid  = threadIdx.x;
    const int b    = blockIdx.x;
    const int c    = tid & 63;
    const int quad = tid >> 6;
    const int r0 = quad*2, r1 = r0 + 1;
    float wreg[CC];

    #pragma unroll
    for (int i = 0; i < 16; ++i)
        *(float4*)&wreg[i*4] = *(const float4*)(spw + c*CC + i*4);
    upd[r0*CC + c] = upd_g[(b*SS + r0)*CC + c];
    upd[r1*CC + c] = upd_g[(b*SS + r1)*CC + c];
    __syncthreads();

    // P1: slot_proj
    {
        const float bias = spb[c];
        float a0 = bias, a1 = bias;
        #pragma unroll
        for (int i = 0; i < 16; ++i) {
            float4 u0 = *(const float4*)&upd[r0*CC + i*4];
            float4 u1 = *(const float4*)&upd[r1*CC + i*4];
            a0 += u0.x*wreg[i*4+0] + u0.y*wreg[i*4+1] + u0.z*wreg[i*4+2] + u0.w*wreg[i*4+3];
            a1 += u1.x*wreg[i*4+0] + u1.y*wreg[i*4+1] + u1.z*wreg[i*4+2] + u1.w*wreg[i*4+3];
        }
        st[r0*CC + c] = a0;
        st[r1*CC + c] = a1;
    }
    __syncthreads();

    // P2: LayerNorm (32 threads per row)
    {
        const int row = tid >> 5, l = tid & 31;
        float v0 = st[row*CC + l], v1 = st[row*CC + l + 32];
        float sum = v0 + v1;
        sum += __shfl_xor(sum, 1); sum += __shfl_xor(sum, 2); sum += __shfl_xor(sum, 4);
        sum += __shfl_xor(sum, 8); sum += __shfl_xor(sum, 16);
        const float mu = sum * (1.f/64.f);
        const float d0 = v0 - mu, d1 = v1 - mu;
        float vs = d0*d0 + d1*d1;
        vs += __shfl_xor(vs, 1); vs += __shfl_xor(vs, 2); vs += __shfl_xor(vs, 4);
        vs += __shfl_xor(vs, 8); vs += __shfl_xor(vs, 16);
        const float rstd = rsqrtf(vs * (1.f/64.f) + 1e-5f);
        snb[row*CC + l]      = d0 * rstd * lng[l]      + lnb[l];
        snb[row*CC + l + 32] = d1 * rstd * lng[l + 32] + lnb[l + 32];
    }
    __syncthreads();

    // P3: qkv
    for (int m = 0; m < 3; ++m) {
        #pragma unroll
        for (int i = 0; i < 16; ++i)
            *(float4*)&wreg[i*4] = *(const float4*)(ipw + (size_t)(m*CC + c)*CC + i*4);
        const float bias = ipb[m*CC + c];
        float a0 = bias, a1 = bias;
        #pragma unroll
        for (int i = 0; i < 16; ++i) {
            float4 u0 = *(const float4*)&snb[r0*CC + i*4];
            float4 u1 = *(const float4*)&snb[r1*CC + i*4];
            a0 += u0.x*wreg[i*4+0] + u0.y*wreg[i*4+1] + u0.z*wreg[i*4+2] + u0.w*wreg[i*4+3];
            a1 += u1.x*wreg[i*4+0] + u1.y*wreg[i*4+1] + u1.z*wreg[i*4+2] + u1.w*wreg[i*4+3];
        }
        qkv[r0*3*CC + m*CC + c] = a0;
        qkv[r1*3*CC + m*CC + c] = a1;
    }
    __syncthreads();

    // P4: MHSA, 32 threads = (h,q)
    if (tid < NH_*SS) {
        const int h = tid >> 3, q = tid & 7;
        float qreg[HD_];
        #pragma unroll
        for (int i = 0; i < 4; ++i)
            *(float4*)&qreg[i*4] = *(const float4*)&qkv[q*3*CC + h*HD_ + i*4];
        float srow[SS];
        float mx = -1e30f;
        #pragma unroll
        for (int k = 0; k < SS; ++k) {
            float acc = 0.f;
            #pragma unroll
            for (int d = 0; d < HD_; ++d)
                acc += qreg[d] * qkv[k*3*CC + CC + h*HD_ + d];
            srow[k] = acc * 0.25f;
            mx = fmaxf(mx, srow[k]);
        }
        float l = 0.f;
        #pragma unroll
        for (int k = 0; k < SS; ++k) { srow[k] = __expf(srow[k] - mx); l += srow[k]; }
        const float inv = 1.f / l;
        float oreg[HD_];
        #pragma unroll
        for (int d = 0; d < HD_; ++d) oreg[d] = 0.f;
        #pragma unroll
        for (int k = 0; k < SS; ++k) {
            #pragma unroll
            for (int d = 0; d < HD_; ++d)
                oreg[d] += srow[k] * qkv[k*3*CC + 2*CC + h*HD_ + d];
        }
        #pragma unroll
        for (int d = 0; d < HD_; ++d)
            ot[q*CC + h*HD_ + d] = oreg[d] * inv;
    }
    __syncthreads();

    // P5: out_proj + residual
    #pragma unroll
    for (int i = 0; i < 16; ++i)
        *(float4*)&wreg[i*4] = *(const float4*)(opw + c*CC + i*4);
    {
        const float bias = opb[c];
        float a0 = bias, a1 = bias;
        #pragma unroll
        for (int i = 0; i < 16; ++i) {
            float4 u0 = *(const float4*)&ot[r0*CC + i*4];
            float4 u1 = *(const float4*)&ot[r1*CC + i*4];
            a0 += u0.x*wreg[i*4+0] + u0.y*wreg[i*4+1] + u0.z*wreg[i*4+2] + u0.w*wreg[i*4+3];
            a1 += u1.x*wreg[i*4+0] + u1.y*wreg[i*4+1] + u1.z*wreg[i*4+2] + u1.w*wreg[i*4+3];
        }
        st[r0*CC + c] += a0;
        st[r1*CC + c] += a1;
    }
    __syncthreads();

    // P6: g = st @ M + g0 ; emit st ; h = st.hv + h0
    #pragma unroll 8
    for (int cp = 0; cp < CC; ++cp) wreg[cp] = M[cp*CC + c];
    {
        const float g0 = g0v[c];
        float a0 = g0, a1 = g0;
        #pragma unroll
        for (int i = 0; i < 16; ++i) {
            float4 s0 = *(const float4*)&st[r0*CC + i*4];
            float4 s1 = *(const float4*)&st[r1*CC + i*4];
            a0 += s0.x*wreg[i*4+0] + s0.y*wreg[i*4+1] + s0.z*wreg[i*4+2] + s0.w*wreg[i*4+3];
            a1 += s1.x*wreg[i*4+0] + s1.y*wreg[i*4+1] + s1.z*wreg[i*4+2] + s1.w*wreg[i*4+3];
        }
        g_out[(b*SS + r0)*CC + c] = a0;
        g_out[(b*SS + r1)*CC + c] = a1;
        st_out[(b*SS + r0)*CC + c] = st[r0*CC + c];
        st_out[(b*SS + r1)*CC + c] = st[r1*CC + c];
    }
    {
        const int row = tid >> 5, l = tid & 31;
        float pv = st[row*CC + l]*hv[l] + st[row*CC + l + 32]*hv[l + 32];
        pv += __shfl_xor(pv, 1); pv += __shfl_xor(pv, 2); pv += __shfl_xor(pv, 4);
        pv += __shfl_xor(pv, 8); pv += __shfl_xor(pv, 16);
        if (l == 0) h_out[b*SS + row] = pv + *h0;
    }
}

// ---------------------------------------------------------------------------
// Kernel C: stage-3 fused pass. (unchanged)
// ---------------------------------------------------------------------------
__global__ __launch_bounds__(256) void k_feat(
    const float* __restrict__ x,
    const float* __restrict__ st_g, const float* __restrict__ g_g,
    const float* __restrict__ h_g,
    float* __restrict__ out)
{
    __shared__ float stS[SS*CC];
    __shared__ float gS [SS*CC];
    __shared__ float hS [SS];

    const int tid = threadIdx.x;
    const int b  = blockIdx.x >> 9;
    const int n  = ((blockIdx.x & 511) << 8) + tid;

    for (int i = tid; i < SS*CC; i += 256) {
        stS[i] = st_g[b*SS*CC + i];
        gS[i]  = g_g [b*SS*CC + i];
    }
    if (tid < SS) hS[tid] = h_g[b*SS + tid];
    __syncthreads();

    const float* xb = x + (size_t)b * CC * NN + n;
    float xc[CC];
    #pragma unroll
    for (int c = 0; c < CC; ++c) xc[c] = xb[(size_t)c * NN];

    float a[SS];
    #pragma unroll
    for (int s = 0; s < SS; ++s) a[s] = hS[s];
    #pragma unroll
    for (int c4 = 0; c4 < CC/4; ++c4) {
        #pragma unroll
        for (int s = 0; s < SS; ++s) {
            float4 g4 = *(const float4*)(&gS[s*CC + c4*4]);
            a[s] += g4.x*xc[c4*4+0] + g4.y*xc[c4*4+1]
                  + g4.z*xc[c4*4+2] + g4.w*xc[c4*4+3];
        }
    }

    float m = a[0];
    #pragma unroll
    for (int s = 1; s < SS; ++s) m = fmaxf(m, a[s]);
    float l = 0.f;
    #pragma unroll
    for (int s = 0; s < SS; ++s) { a[s] = __expf(a[s] - m); l += a[s]; }
    const float inv = 1.f / l;

    float* ob = out + (size_t)b * CC * NN + n;
    #pragma unroll
    for (int c4 = 0; c4 < CC/4; ++c4) {
        float o0 = 0.f, o1 = 0.f, o2 = 0.f, o3 = 0.f;
        #pragma unroll
        for (int s = 0; s < SS; ++s) {
            float4 s4 = *(const float4*)(&stS[s*CC + c4*4]);
            o0 += s4.x * a[s]; o1 += s4.y * a[s];
            o2 += s4.z * a[s]; o3 += s4.w * a[s];
        }
        ob[(size_t)(c4*4+0) * NN] = o0 * inv + xc[c4*4+0];
        ob[(size_t)(c4*4+1) * NN] = o1 * inv + xc[c4*4+1];
        ob[(size_t)(c4*4+2) * NN] = o2 * inv + xc[c4*4+2];
        ob[(size_t)(c4*4+3) * NN] = o3 * inv + xc[c4*4+3];
    }
}

// ---------------------------------------------------------------------------
extern "C" void kernel_launch(void* const* d_in, const int* in_sizes, int n_in,
                              void* d_out, int out_size, void* d_ws, size_t ws_size,
                              hipStream_t stream) {
    const float* x         = (const float*)d_in[0];
    const float* slot_init = (const float*)d_in[1];
    const float* spw       = (const float*)d_in[2];
    const float* spb       = (const float*)d_in[3];
    const float* lng       = (const float*)d_in[4];
    const float* lnb       = (const float*)d_in[5];
    const float* ipw       = (const float*)d_in[6];
    const float* ipb       = (const float*)d_in[7];
    const float* opw       = (const float*)d_in[8];
    const float* opb       = (const float*)d_in[9];
    const float* fw        = (const float*)d_in[10];
    const float* fb        = (const float*)d_in[11];
    const float* s2fw      = (const float*)d_in[12];
    const float* s2fb      = (const float*)d_in[13];
    float* out = (float*)d_out;

    // workspace layout (floats)
    float* w         = (float*)d_ws;
    float* U_part    = w;                       // 4*128*8*64 = 262144
    float* sume_part = w + 262144;              // 4096
    float* upd_g     = w + 266240;              // 2048
    float* Mm        = w + 268288;              // 4096
    float* g0v       = w + 272384;              // 64
    float* hv        = w + 272448;              // 64
    float* h0        = w + 272512;              // 64 (1 used)
    float* st_out    = w + 272576;              // 2048
    float* g_out     = w + 274624;              // 2048
    float* h_out     = w + 276672;              // 32

    k_precomp<<<17, 256, 0, stream>>>(s2fw, s2fb, fw, fb, Mm, g0v, hv, h0);
    k_slots_attn<<<BB * BPB, 512, 0, stream>>>(x, slot_init, U_part, sume_part);
    k_reduce2<<<BB * SS, 256, 0, stream>>>(U_part, sume_part, upd_g);
    k_slots_small<<<BB, 256, 0, stream>>>(upd_g, spw, spb, lng, lnb,
                                          ipw, ipb, opw, opb, Mm, g0v, hv, h0,
                                          st_out, g_out, h_out);
    k_feat<<<BB * (NN/256), 256, 0, stream>>>(x, st_out, g_out, h_out, out);
}

// Round 6
// 144.065 us; speedup vs baseline: 1.2271x; 1.2271x over previous
//
#include <hip/hip_runtime.h>
#include <hip/hip_bf16.h>

// Problem constants
#define BB   4
#define CC   64
#define SS   8
#define NN   (32*64*64)   // 131072
#define NH_  4
#define HD_  16
#define TN   256          // n-tile for stage-1 kernel

typedef __attribute__((ext_vector_type(8))) short bf16x8;
typedef __attribute__((ext_vector_type(4))) float f32x4;

__device__ __forceinline__ float b2f(unsigned short h) {
    union { unsigned u; float f; } v; v.u = ((unsigned)h) << 16; return v.f;
}
__device__ __forceinline__ unsigned short f2b(float f) {
    union { float f; unsigned u; } v; v.f = f;
    unsigned r = v.u + 0x7FFFu + ((v.u >> 16) & 1u);
    return (unsigned short)(r >> 16);
}
__device__ __forceinline__ unsigned bfpack(float a, float b) {   // a->low, b->high
    union { float f; unsigned u; } x, y; x.f = a; y.f = b;
    unsigned ra = (x.u + 0x7FFFu + ((x.u >> 16) & 1u)) >> 16;
    unsigned rb = (y.u + 0x7FFFu + ((y.u >> 16) & 1u)) & 0xFFFF0000u;
    return ra | rb;
}

// ---------------------------------------------------------------------------
// Kernel A: stage-1 pass over x.  256 threads, bf16 LDS tile, MFMA accumulate.
// Per (b,n): e_s = exp(<sn_s, x/||x||>)  (sim in [-1,1] -> drop max-subtract)
// U^T(c,s) += xt(16c x 32n) @ et^T(32n x 16s) via mfma_f32_16x16x32_bf16;
// accumulators live in VGPRs across the whole tile loop.
// 16B-slot XOR swizzle (slot ^ row&7) on xt and et keeps every access at the
// structural bank floor. et rows 8..15 zeroed once (padded B-operand).
// ---------------------------------------------------------------------------
__global__ __launch_bounds__(256) void k_slots_attn(
    const float* __restrict__ x, const float* __restrict__ slot_init,
    float* __restrict__ U_part, float* __restrict__ sume_part, int bpb)
{
    __shared__ short xt[CC * TN];      // 32 KB bf16, swizzled 16B slots
    __shared__ short et[16 * TN];      // 8 KB bf16, rows 8..15 zero
    __shared__ float snT[SS * CC];     // 2 KB [s][c]
    __shared__ float snorm[SS];
    __shared__ float red[SS * 256];    // 8 KB accS reduce

    const int tid = threadIdx.x;
    const int b   = blockIdx.x / bpb;
    const int blk = blockIdx.x % bpb;

    // zero et rows 8..15 (once)
    *(int4*)&et[8*TN + tid*8] = make_int4(0, 0, 0, 0);

    // normalized slot vectors (slot_init is (1,C,S) -> same for all b)
    if (tid < SS) {
        float ss = 0.f;
        for (int c = 0; c < CC; ++c) { float v = slot_init[c*SS + tid]; ss += v*v; }
        snorm[tid] = fmaxf(sqrtf(ss), 1e-12f);
    }
    __syncthreads();
    if (tid < CC) {
        for (int s = 0; s < SS; ++s) snT[s*CC + tid] = slot_init[tid*SS + s] / snorm[s];
    }
    __syncthreads();

    const int lane = tid & 63, wv = tid >> 6;
    const int cS = tid >> 2, nq = tid & 3;    // staging: row, col-quarter
    f32x4 accU = {0.f, 0.f, 0.f, 0.f};
    float accS[SS];
    #pragma unroll
    for (int s = 0; s < SS; ++s) accS[s] = 0.f;

    const float* xb = x + (size_t)b * CC * NN;
    const int ntiles = NN / TN;        // 512

    for (int t = blk; t < ntiles; t += bpb) {
        const int n0 = t * TN;

        // ---- stage: global float4x2 -> bf16 swizzled LDS ----
        {
            const float* srcrow = xb + (size_t)cS * NN + n0;
            #pragma unroll
            for (int i = 0; i < 8; ++i) {
                const int n = nq*8 + i*32;
                float4 va = *(const float4*)(srcrow + n);
                float4 vb = *(const float4*)(srcrow + n + 4);
                int4 o;
                o.x = (int)bfpack(va.x, va.y);
                o.y = (int)bfpack(va.z, va.w);
                o.z = (int)bfpack(vb.x, vb.y);
                o.w = (int)bfpack(vb.z, vb.w);
                const int slot = (nq + i*4) ^ (cS & 7);
                *(int4*)&xt[cS*TN + (slot << 3)] = o;
            }
        }
        __syncthreads();

        // ---- dots: thread owns column n = tid ----
        {
            const int nq3 = tid >> 3, n7 = tid & 7;
            float ss = 0.f;
            float a[SS];
            #pragma unroll
            for (int s = 0; s < SS; ++s) a[s] = 0.f;
            #pragma unroll
            for (int c4 = 0; c4 < 16; ++c4) {
                float xv[4];
                #pragma unroll
                for (int j = 0; j < 4; ++j) {
                    const int c = c4*4 + j;
                    unsigned short h = (unsigned short)xt[c*TN + (((nq3 ^ (c & 7)) << 3) | n7)];
                    xv[j] = b2f(h);
                    ss += xv[j] * xv[j];
                }
                #pragma unroll
                for (int s = 0; s < SS; ++s) {
                    const float4 g4 = *(const float4*)&snT[s*CC + c4*4];
                    a[s] += g4.x*xv[0] + g4.y*xv[1] + g4.z*xv[2] + g4.w*xv[3];
                }
            }
            const float invn = 1.f / fmaxf(sqrtf(ss), 1e-12f);
            #pragma unroll
            for (int s = 0; s < SS; ++s) {
                float e = __expf(a[s] * invn);
                accS[s] += e;
                et[s*TN + (((nq3 ^ s) << 3) | n7)] = (short)f2b(e);
            }
        }
        __syncthreads();

        // ---- MFMA accumulate: wave wv owns c-tile [16wv,16wv+16) ----
        {
            const int ca = (wv << 4) + (lane & 15);   // xt row (c)
            const int rb = lane & 15;                 // et row (s; 8..15 = zeros)
            const int p  = lane >> 4;
            #pragma unroll
            for (int k = 0; k < TN/32; ++k) {
                const int sa = ((((k << 2) + p) ^ (lane & 7)) << 3);
                bf16x8 af = *(const bf16x8*)&xt[ca*TN + sa];
                bf16x8 bfr = *(const bf16x8*)&et[rb*TN + sa];
                accU = __builtin_amdgcn_mfma_f32_16x16x32_bf16(af, bfr, accU, 0, 0, 0);
            }
        }
        __syncthreads();
    }

    // ---- write U^T partials: D col = lane&15 = s, row = (lane>>4)*4+reg = c-off
    {
        const size_t base = ((size_t)(b*bpb + blk) * SS) * CC;
        if ((lane & 15) < SS) {
            const int s  = lane & 15;
            const int c0 = (wv << 4) + ((lane >> 4) << 2);
            #pragma unroll
            for (int r = 0; r < 4; ++r)
                U_part[base + s*CC + c0 + r] = accU[r];
        }
    }
    // ---- accS block reduce ----
    #pragma unroll
    for (int s = 0; s < SS; ++s) red[s*256 + tid] = accS[s];
    __syncthreads();
    {
        const int s = tid >> 5, j = tid & 31;
        float v = 0.f;
        #pragma unroll
        for (int k = 0; k < 8; ++k) v += red[s*256 + j*8 + k];
        v += __shfl_xor(v, 1); v += __shfl_xor(v, 2); v += __shfl_xor(v, 4);
        v += __shfl_xor(v, 8); v += __shfl_xor(v, 16);
        if (j == 0) sume_part[(size_t)(b*bpb + blk)*SS + s] = v;
    }
}

// ---------------------------------------------------------------------------
// Kernel P: precompute slot-independent folds of the feature path.
// ---------------------------------------------------------------------------
__global__ __launch_bounds__(256) void k_precomp(
    const float* __restrict__ s2fw, const float* __restrict__ s2fb,
    const float* __restrict__ fw, const float* __restrict__ fb,
    float* __restrict__ M, float* __restrict__ g0v,
    float* __restrict__ hv, float* __restrict__ h0)
{
    const int tid = threadIdx.x;
    if (blockIdx.x < 16) {
        const int cp = blockIdx.x*4 + (tid >> 6);
        const int c  = tid & 63;
        float acc = 0.f;
        #pragma unroll 8
        for (int o = 0; o < CC; ++o)
            acc += s2fw[o*CC + cp] * fw[o*CC + c];
        M[cp*CC + c] = acc;
    } else {
        if (tid < 64) {
            float acc = 0.f;
            #pragma unroll 8
            for (int o = 0; o < CC; ++o) acc += s2fb[o] * fw[o*CC + tid];
            g0v[tid] = acc;
        } else if (tid < 128) {
            const int cp = tid - 64;
            float acc = 0.f;
            #pragma unroll 8
            for (int o = 0; o < CC; ++o) acc += s2fw[o*CC + cp] * fb[o];
            hv[cp] = acc;
        } else if (tid == 128) {
            float acc = 0.f;
            for (int o = 0; o < CC; ++o) acc += s2fb[o] * fb[o];
            *h0 = acc;
        }
    }
}

// ---------------------------------------------------------------------------
// Kernel R: parallel reduce of partials -> upd[b,s,c] = U/L directly.
// ---------------------------------------------------------------------------
__global__ __launch_bounds__(256) void k_reduce2(
    const float* __restrict__ U_part, const float* __restrict__ sume_part,
    float* __restrict__ upd_g, int bpb)
{
    __shared__ float part[4][64];
    __shared__ float lbuf[256];
    __shared__ float Lsh;
    const int tid = threadIdx.x;
    const int b = blockIdx.x >> 3, s = blockIdx.x & 7;
    const int c = tid & 63, kc = tid >> 6;
    const int cnt = bpb >> 2;

    lbuf[tid] = (tid < bpb) ? sume_part[(size_t)(b*bpb + tid)*SS + s] : 0.f;

    float acc = 0.f;
    const float* base = U_part + ((size_t)(b*bpb + kc*cnt)*SS + s)*CC + c;
    for (int k = 0; k < cnt; ++k)
        acc += base[(size_t)k * SS * CC];
    part[kc][c] = acc;
    __syncthreads();

    if (tid < 128) lbuf[tid] += lbuf[tid + 128];
    __syncthreads();
    if (tid < 64) {
        float v = lbuf[tid] + lbuf[tid + 64];
        v += __shfl_xor(v, 1); v += __shfl_xor(v, 2); v += __shfl_xor(v, 4);
        v += __shfl_xor(v, 8); v += __shfl_xor(v, 16); v += __shfl_xor(v, 32);
        if (tid == 0) Lsh = v;
    }
    __syncthreads();

    if (tid < 64) {
        float u = part[0][c] + part[1][c] + part[2][c] + part[3][c];
        upd_g[((size_t)b*SS + s)*CC + c] = u / Lsh;
    }
}

// ---------------------------------------------------------------------------
// Kernel B: slot pipeline. 4 blocks (one per batch), 256 threads.
// ---------------------------------------------------------------------------
__global__ __launch_bounds__(256) void k_slots_small(
    const float* __restrict__ upd_g,
    const float* __restrict__ spw, const float* __restrict__ spb,
    const float* __restrict__ lng, const float* __restrict__ lnb,
    const float* __restrict__ ipw, const float* __restrict__ ipb,
    const float* __restrict__ opw, const float* __restrict__ opb,
    const float* __restrict__ M, const float* __restrict__ g0v,
    const float* __restrict__ hv, const float* __restrict__ h0,
    float* __restrict__ st_out, float* __restrict__ g_out, float* __restrict__ h_out)
{
    __shared__ float upd[SS*CC];
    __shared__ float st [SS*CC];
    __shared__ float snb[SS*CC];
    __shared__ float qkv[SS*3*CC];
    __shared__ float ot [SS*CC];

    const int tid  = threadIdx.x;
    const int b    = blockIdx.x;
    const int c    = tid & 63;
    const int quad = tid >> 6;
    const int r0 = quad*2, r1 = r0 + 1;
    float wreg[CC];

    #pragma unroll
    for (int i = 0; i < 16; ++i)
        *(float4*)&wreg[i*4] = *(const float4*)(spw + c*CC + i*4);
    upd[r0*CC + c] = upd_g[(b*SS + r0)*CC + c];
    upd[r1*CC + c] = upd_g[(b*SS + r1)*CC + c];
    __syncthreads();

    // P1: slot_proj
    {
        const float bias = spb[c];
        float a0 = bias, a1 = bias;
        #pragma unroll
        for (int i = 0; i < 16; ++i) {
            float4 u0 = *(const float4*)&upd[r0*CC + i*4];
            float4 u1 = *(const float4*)&upd[r1*CC + i*4];
            a0 += u0.x*wreg[i*4+0] + u0.y*wreg[i*4+1] + u0.z*wreg[i*4+2] + u0.w*wreg[i*4+3];
            a1 += u1.x*wreg[i*4+0] + u1.y*wreg[i*4+1] + u1.z*wreg[i*4+2] + u1.w*wreg[i*4+3];
        }
        st[r0*CC + c] = a0;
        st[r1*CC + c] = a1;
    }
    __syncthreads();

    // P2: LayerNorm (32 threads per row)
    {
        const int row = tid >> 5, l = tid & 31;
        float v0 = st[row*CC + l], v1 = st[row*CC + l + 32];
        float sum = v0 + v1;
        sum += __shfl_xor(sum, 1); sum += __shfl_xor(sum, 2); sum += __shfl_xor(sum, 4);
        sum += __shfl_xor(sum, 8); sum += __shfl_xor(sum, 16);
        const float mu = sum * (1.f/64.f);
        const float d0 = v0 - mu, d1 = v1 - mu;
        float vs = d0*d0 + d1*d1;
        vs += __shfl_xor(vs, 1); vs += __shfl_xor(vs, 2); vs += __shfl_xor(vs, 4);
        vs += __shfl_xor(vs, 8); vs += __shfl_xor(vs, 16);
        const float rstd = rsqrtf(vs * (1.f/64.f) + 1e-5f);
        snb[row*CC + l]      = d0 * rstd * lng[l]      + lnb[l];
        snb[row*CC + l + 32] = d1 * rstd * lng[l + 32] + lnb[l + 32];
    }
    __syncthreads();

    // P3: qkv
    for (int m = 0; m < 3; ++m) {
        #pragma unroll
        for (int i = 0; i < 16; ++i)
            *(float4*)&wreg[i*4] = *(const float4*)(ipw + (size_t)(m*CC + c)*CC + i*4);
        const float bias = ipb[m*CC + c];
        float a0 = bias, a1 = bias;
        #pragma unroll
        for (int i = 0; i < 16; ++i) {
            float4 u0 = *(const float4*)&snb[r0*CC + i*4];
            float4 u1 = *(const float4*)&snb[r1*CC + i*4];
            a0 += u0.x*wreg[i*4+0] + u0.y*wreg[i*4+1] + u0.z*wreg[i*4+2] + u0.w*wreg[i*4+3];
            a1 += u1.x*wreg[i*4+0] + u1.y*wreg[i*4+1] + u1.z*wreg[i*4+2] + u1.w*wreg[i*4+3];
        }
        qkv[r0*3*CC + m*CC + c] = a0;
        qkv[r1*3*CC + m*CC + c] = a1;
    }
    __syncthreads();

    // P4: MHSA, 32 threads = (h,q)
    if (tid < NH_*SS) {
        const int h = tid >> 3, q = tid & 7;
        float qreg[HD_];
        #pragma unroll
        for (int i = 0; i < 4; ++i)
            *(float4*)&qreg[i*4] = *(const float4*)&qkv[q*3*CC + h*HD_ + i*4];
        float srow[SS];
        float mx = -1e30f;
        #pragma unroll
        for (int k = 0; k < SS; ++k) {
            float acc = 0.f;
            #pragma unroll
            for (int d = 0; d < HD_; ++d)
                acc += qreg[d] * qkv[k*3*CC + CC + h*HD_ + d];
            srow[k] = acc * 0.25f;
            mx = fmaxf(mx, srow[k]);
        }
        float l = 0.f;
        #pragma unroll
        for (int k = 0; k < SS; ++k) { srow[k] = __expf(srow[k] - mx); l += srow[k]; }
        const float inv = 1.f / l;
        float oreg[HD_];
        #pragma unroll
        for (int d = 0; d < HD_; ++d) oreg[d] = 0.f;
        #pragma unroll
        for (int k = 0; k < SS; ++k) {
            #pragma unroll
            for (int d = 0; d < HD_; ++d)
                oreg[d] += srow[k] * qkv[k*3*CC + 2*CC + h*HD_ + d];
        }
        #pragma unroll
        for (int d = 0; d < HD_; ++d)
            ot[q*CC + h*HD_ + d] = oreg[d] * inv;
    }
    __syncthreads();

    // P5: out_proj + residual
    #pragma unroll
    for (int i = 0; i < 16; ++i)
        *(float4*)&wreg[i*4] = *(const float4*)(opw + c*CC + i*4);
    {
        const float bias = opb[c];
        float a0 = bias, a1 = bias;
        #pragma unroll
        for (int i = 0; i < 16; ++i) {
            float4 u0 = *(const float4*)&ot[r0*CC + i*4];
            float4 u1 = *(const float4*)&ot[r1*CC + i*4];
            a0 += u0.x*wreg[i*4+0] + u0.y*wreg[i*4+1] + u0.z*wreg[i*4+2] + u0.w*wreg[i*4+3];
            a1 += u1.x*wreg[i*4+0] + u1.y*wreg[i*4+1] + u1.z*wreg[i*4+2] + u1.w*wreg[i*4+3];
        }
        st[r0*CC + c] += a0;
        st[r1*CC + c] += a1;
    }
    __syncthreads();

    // P6: g = st @ M + g0 ; emit st ; h = st.hv + h0
    #pragma unroll 8
    for (int cp = 0; cp < CC; ++cp) wreg[cp] = M[cp*CC + c];
    {
        const float g0 = g0v[c];
        float a0 = g0, a1 = g0;
        #pragma unroll
        for (int i = 0; i < 16; ++i) {
            float4 s0 = *(const float4*)&st[r0*CC + i*4];
            float4 s1 = *(const float4*)&st[r1*CC + i*4];
            a0 += s0.x*wreg[i*4+0] + s0.y*wreg[i*4+1] + s0.z*wreg[i*4+2] + s0.w*wreg[i*4+3];
            a1 += s1.x*wreg[i*4+0] + s1.y*wreg[i*4+1] + s1.z*wreg[i*4+2] + s1.w*wreg[i*4+3];
        }
        g_out[(b*SS + r0)*CC + c] = a0;
        g_out[(b*SS + r1)*CC + c] = a1;
        st_out[(b*SS + r0)*CC + c] = st[r0*CC + c];
        st_out[(b*SS + r1)*CC + c] = st[r1*CC + c];
    }
    {
        const int row = tid >> 5, l = tid & 31;
        float pv = st[row*CC + l]*hv[l] + st[row*CC + l + 32]*hv[l + 32];
        pv += __shfl_xor(pv, 1); pv += __shfl_xor(pv, 2); pv += __shfl_xor(pv, 4);
        pv += __shfl_xor(pv, 8); pv += __shfl_xor(pv, 16);
        if (l == 0) h_out[b*SS + row] = pv + *h0;
    }
}

// ---------------------------------------------------------------------------
// Kernel C: stage-3 fused pass. (unchanged)
// ---------------------------------------------------------------------------
__global__ __launch_bounds__(256) void k_feat(
    const float* __restrict__ x,
    const float* __restrict__ st_g, const float* __restrict__ g_g,
    const float* __restrict__ h_g,
    float* __restrict__ out)
{
    __shared__ float stS[SS*CC];
    __shared__ float gS [SS*CC];
    __shared__ float hS [SS];

    const int tid = threadIdx.x;
    const int b  = blockIdx.x >> 9;
    const int n  = ((blockIdx.x & 511) << 8) + tid;

    for (int i = tid; i < SS*CC; i += 256) {
        stS[i] = st_g[b*SS*CC + i];
        gS[i]  = g_g [b*SS*CC + i];
    }
    if (tid < SS) hS[tid] = h_g[b*SS + tid];
    __syncthreads();

    const float* xb = x + (size_t)b * CC * NN + n;
    float xc[CC];
    #pragma unroll
    for (int c = 0; c < CC; ++c) xc[c] = xb[(size_t)c * NN];

    float a[SS];
    #pragma unroll
    for (int s = 0; s < SS; ++s) a[s] = hS[s];
    #pragma unroll
    for (int c4 = 0; c4 < CC/4; ++c4) {
        #pragma unroll
        for (int s = 0; s < SS; ++s) {
            float4 g4 = *(const float4*)(&gS[s*CC + c4*4]);
            a[s] += g4.x*xc[c4*4+0] + g4.y*xc[c4*4+1]
                  + g4.z*xc[c4*4+2] + g4.w*xc[c4*4+3];
        }
    }

    float m = a[0];
    #pragma unroll
    for (int s = 1; s < SS; ++s) m = fmaxf(m, a[s]);
    float l = 0.f;
    #pragma unroll
    for (int s = 0; s < SS; ++s) { a[s] = __expf(a[s] - m); l += a[s]; }
    const float inv = 1.f / l;

    float* ob = out + (size_t)b * CC * NN + n;
    #pragma unroll
    for (int c4 = 0; c4 < CC/4; ++c4) {
        float o0 = 0.f, o1 = 0.f, o2 = 0.f, o3 = 0.f;
        #pragma unroll
        for (int s = 0; s < SS; ++s) {
            float4 s4 = *(const float4*)(&stS[s*CC + c4*4]);
            o0 += s4.x * a[s]; o1 += s4.y * a[s];
            o2 += s4.z * a[s]; o3 += s4.w * a[s];
        }
        ob[(size_t)(c4*4+0) * NN] = o0 * inv + xc[c4*4+0];
        ob[(size_t)(c4*4+1) * NN] = o1 * inv + xc[c4*4+1];
        ob[(size_t)(c4*4+2) * NN] = o2 * inv + xc[c4*4+2];
        ob[(size_t)(c4*4+3) * NN] = o3 * inv + xc[c4*4+3];
    }
}

// ---------------------------------------------------------------------------
extern "C" void kernel_launch(void* const* d_in, const int* in_sizes, int n_in,
                              void* d_out, int out_size, void* d_ws, size_t ws_size,
                              hipStream_t stream) {
    const float* x         = (const float*)d_in[0];
    const float* slot_init = (const float*)d_in[1];
    const float* spw       = (const float*)d_in[2];
    const float* spb       = (const float*)d_in[3];
    const float* lng       = (const float*)d_in[4];
    const float* lnb       = (const float*)d_in[5];
    const float* ipw       = (const float*)d_in[6];
    const float* ipb       = (const float*)d_in[7];
    const float* opw       = (const float*)d_in[8];
    const float* opb       = (const float*)d_in[9];
    const float* fw        = (const float*)d_in[10];
    const float* fb        = (const float*)d_in[11];
    const float* s2fw      = (const float*)d_in[12];
    const float* s2fb      = (const float*)d_in[13];
    float* out = (float*)d_out;

    // choose bpb (blocks per batch) by available workspace; 128 is known-fit
    int bpb = 192;
    {
        size_t need = ((size_t)BB*bpb*SS*CC + (size_t)BB*bpb*SS
                       + 2048 + 4096 + 64 + 64 + 64 + 2048 + 2048 + 32) * sizeof(float);
        if (need > ws_size) bpb = 128;
    }

    float* w         = (float*)d_ws;
    float* U_part    = w;
    float* sume_part = U_part + (size_t)BB*bpb*SS*CC;
    float* upd_g     = sume_part + (size_t)BB*bpb*SS;
    float* Mm        = upd_g + 2048;
    float* g0v       = Mm + 4096;
    float* hv        = g0v + 64;
    float* h0        = hv + 64;
    float* st_out    = h0 + 64;
    float* g_out     = st_out + 2048;
    float* h_out     = g_out + 2048;

    k_precomp<<<17, 256, 0, stream>>>(s2fw, s2fb, fw, fb, Mm, g0v, hv, h0);
    k_slots_attn<<<BB * bpb, 256, 0, stream>>>(x, slot_init, U_part, sume_part, bpb);
    k_reduce2<<<BB * SS, 256, 0, stream>>>(U_part, sume_part, upd_g, bpb);
    k_slots_small<<<BB, 256, 0, stream>>>(upd_g, spw, spb, lng, lnb,
                                          ipw, ipb, opw, opb, Mm, g0v, hv, h0,
                                          st_out, g_out, h_out);
    k_feat<<<BB * (NN/256), 256, 0, stream>>>(x, st_out, g_out, h_out, out);
}